// Round 1
// baseline (382.312 us; speedup 1.0000x reference)
//
#include <hip/hip_runtime.h>
#include <stdint.h>

// ---------------------------------------------------------------------------
// RuleModel: logic-gate network forward.
// Forward value of the straight-through gumbel gate is EXACTLY a one-hot
// column selector (hard + y - y). So each h @ gate is a column gather with
// index argmax_i(w[i,j] + g[i,j]).  (softmax monotone, tau=1)
// Pipeline: memset(ws) -> argmax (atomic, packed u64) -> u16 convert -> forward.
// ---------------------------------------------------------------------------

struct GatePtrs {
    const float* w[12];
    const float* g[12];
};

// packed layout in ws: u64 packed[10240]; layer offsets 0 / 4096 / 8192,
// gate slot (c1,c2,d1,d2) stride = dout.
__global__ __launch_bounds__(256) void argmax_kernel(GatePtrs gp,
                                                     unsigned long long* __restrict__ packed) {
    const int dins[3]  = {1026, 3074, 5122};
    const int douts[3] = {1024, 1024, 512};
    const int offs[3]  = {0, 4096, 8192};
    int gate  = blockIdx.z;          // 0..11
    int layer = gate >> 2;
    int din  = dins[layer];
    int dout = douts[layer];
    int col = blockIdx.x * 256 + threadIdx.x;
    int r0  = blockIdx.y * 64;
    if (col >= dout || r0 >= din) return;   // padded grid -> early exit
    int r1 = min(r0 + 64, din);
    const float* __restrict__ w = gp.w[gate];
    const float* __restrict__ g = gp.g[gate];
    float best  = -3.4e38f;
    int bestrow = r0;
    #pragma unroll 4
    for (int i = r0; i < r1; ++i) {
        float v = w[(size_t)i * dout + col] + g[(size_t)i * dout + col];
        if (v > best) { best = v; bestrow = i; }   // strict > keeps first index
    }
    // sortable-float key: monotone map float -> u32
    unsigned int u   = __float_as_uint(best);
    unsigned int key = u ^ ((u & 0x80000000u) ? 0xFFFFFFFFu : 0x80000000u);
    // low word = ~row so that on exact value ties atomicMax picks the SMALLER
    // row (matches jnp.argmax first-occurrence semantics).
    unsigned long long p = ((unsigned long long)key << 32)
                         | (unsigned long long)(0xFFFFFFFFu - (unsigned int)bestrow);
    atomicMax(packed + offs[layer] + (gate & 3) * dout + col, p);
}

__global__ __launch_bounds__(256) void convert_kernel(const unsigned long long* __restrict__ packed,
                                                      unsigned short* __restrict__ idx) {
    int i = blockIdx.x * 256 + threadIdx.x;
    if (i < 10240) {
        unsigned int low = (unsigned int)(packed[i] & 0xFFFFFFFFull);
        idx[i] = (unsigned short)(0xFFFFFFFFu - low);   // recover row index
    }
}

// One block per batch row. h (up to 5122 floats, 20.5 KB) lives in LDS;
// all gate gathers hit LDS. Index array is 20 KB total -> L1-resident.
__global__ __launch_bounds__(256, 7) void forward_kernel(const float* __restrict__ x,
                                                         const float* __restrict__ lin_w,
                                                         const unsigned short* __restrict__ idx,
                                                         float* __restrict__ out) {
    __shared__ float h[5122];
    __shared__ float wsum[4];
    const int row = blockIdx.x;
    const int t   = threadIdx.x;

    // ---- build h0 = [x, 1-x, 1, 0]  (1026 entries) ----
    const float2* xr = (const float2*)(x + (size_t)row * 512);
    float2 v = xr[t];                      // t in [0,256): covers 512 floats
    h[2 * t]           = v.x;
    h[2 * t + 1]       = v.y;
    h[512 + 2 * t]     = 1.0f - v.x;
    h[512 + 2 * t + 1] = 1.0f - v.y;
    if (t == 0) { h[1024] = 1.0f; h[1025] = 0.0f; }
    __syncthreads();

    // ---- layers 1 & 2: each appends 1024 AND-gates + 1024 OR-gates ----
    int len  = 1026;   // current h length
    int ioff = 0;      // index-array offset for this layer
    #pragma unroll
    for (int layer = 0; layer < 2; ++layer) {
        #pragma unroll
        for (int k = 0; k < 4; ++k) {
            int j  = t + k * 256;
            int i1 = idx[ioff +        j];
            int i2 = idx[ioff + 1024 + j];
            int i3 = idx[ioff + 2048 + j];
            int i4 = idx[ioff + 3072 + j];
            float c = h[i1] * h[i2];                          // AND
            float a = h[i3], b = h[i4];
            float d = 1.0f - (1.0f - a) * (1.0f - b);         // OR
            h[len +        j] = c;   // writes land past [0,len): no race w/ reads
            h[len + 1024 + j] = d;
        }
        __syncthreads();
        len  += 2048;   // 3074 after layer1, 5122 after layer2
        ioff += 4096;
    }

    // ---- layer 3 (512 AND + 512 OR), fused with lin_w dot ----
    float sum = 0.0f;
    #pragma unroll
    for (int k = 0; k < 2; ++k) {
        int j  = t + k * 256;
        int i1 = idx[8192 +        j];
        int i2 = idx[8192 +  512 + j];
        int i3 = idx[8192 + 1024 + j];
        int i4 = idx[8192 + 1536 + j];
        float c = h[i1] * h[i2];
        float a = h[i3], b = h[i4];
        float d = 1.0f - (1.0f - a) * (1.0f - b);
        sum += lin_w[j] * c + lin_w[512 + j] * d;
    }

    // ---- block reduction ----
    #pragma unroll
    for (int off = 32; off > 0; off >>= 1)
        sum += __shfl_down(sum, off, 64);
    if ((t & 63) == 0) wsum[t >> 6] = sum;
    __syncthreads();
    if (t == 0) out[row] = wsum[0] + wsum[1] + wsum[2] + wsum[3];
}

extern "C" void kernel_launch(void* const* d_in, const int* in_sizes, int n_in,
                              void* d_out, int out_size, void* d_ws, size_t ws_size,
                              hipStream_t stream) {
    // d_in layout (setup_inputs order): [0..7] l1 wc1,wc2,wd1,wd2,gc1,gc2,gd1,gd2;
    // [8..15] l2; [16..23] l3; [24] x (32768x512); [25] lin_w (1024); [26] tau.
    GatePtrs gp;
    for (int l = 0; l < 3; ++l) {
        for (int s = 0; s < 4; ++s) {
            gp.w[l * 4 + s] = (const float*)d_in[l * 8 + s];
            gp.g[l * 4 + s] = (const float*)d_in[l * 8 + 4 + s];
        }
    }
    const float* x     = (const float*)d_in[24];
    const float* lin_w = (const float*)d_in[25];
    float* out = (float*)d_out;

    unsigned long long* packed = (unsigned long long*)d_ws;
    unsigned short* idx = (unsigned short*)((char*)d_ws + 10240 * sizeof(unsigned long long));

    // init packed argmax keys to 0 (below any real sortable-float key)
    hipMemsetAsync(d_ws, 0, 10240 * sizeof(unsigned long long), stream);

    // argmax over rows of w+g, 64-row chunks; padded 3D grid with guards
    dim3 gridA(4 /*col blocks*/, 81 /*max row chunks*/, 12 /*gates*/);
    argmax_kernel<<<gridA, 256, 0, stream>>>(gp, packed);

    convert_kernel<<<40, 256, 0, stream>>>(packed, idx);

    forward_kernel<<<32768, 256, 0, stream>>>(x, lin_w, idx, out);
}

// Round 2
// 368.776 us; speedup vs baseline: 1.0367x; 1.0367x over previous
//
#include <hip/hip_runtime.h>
#include <stdint.h>

// ---------------------------------------------------------------------------
// RuleModel forward. ST-gumbel gate forward == exact one-hot column selector,
// so each h @ gate is a gather with index argmax_i(w[i,j]+g[i,j]).
// Pipeline: memset(ws) -> argmax (packed u64 atomics) -> convert (pair byte
// offsets) -> forward (2 rows/block, float2-interleaved h in LDS: gate index
// is shared across rows -> ds_read_b64 serves both rows, halving gather count
// and amortizing index/VALU cost).
// ---------------------------------------------------------------------------

struct GatePtrs {
    const float* w[12];
    const float* g[12];
};

// packed layout in ws: u64 packed[10240]; layer offsets 0 / 4096 / 8192,
// gate slot (c1,c2,d1,d2) stride = dout.
__global__ __launch_bounds__(256) void argmax_kernel(GatePtrs gp,
                                                     unsigned long long* __restrict__ packed) {
    const int dins[3]  = {1026, 3074, 5122};
    const int douts[3] = {1024, 1024, 512};
    const int offs[3]  = {0, 4096, 8192};
    int gate  = blockIdx.z;          // 0..11
    int layer = gate >> 2;
    int din  = dins[layer];
    int dout = douts[layer];
    int c2 = blockIdx.x * 256 + threadIdx.x;   // column PAIR index
    int r0 = blockIdx.y * 64;
    if (2 * c2 >= dout || r0 >= din) return;   // padded grid -> early exit
    int r1 = min(r0 + 64, din);
    const float* __restrict__ w = gp.w[gate];
    const float* __restrict__ g = gp.g[gate];
    float bx = -3.4e38f, by = -3.4e38f;
    int rx = r0, ry = r0;
    #pragma unroll 8
    for (int i = r0; i < r1; ++i) {
        float2 wv = *(const float2*)(w + (size_t)i * dout + 2 * c2);
        float2 gv = *(const float2*)(g + (size_t)i * dout + 2 * c2);
        float vx = wv.x + gv.x, vy = wv.y + gv.y;
        if (vx > bx) { bx = vx; rx = i; }      // strict > keeps first index
        if (vy > by) { by = vy; ry = i; }
    }
    unsigned long long* dst = packed + offs[layer] + (gate & 3) * dout + 2 * c2;
    // sortable-float key; low word = ~row so value-ties pick the smaller row
    unsigned int ux = __float_as_uint(bx);
    unsigned int kx = ux ^ ((ux & 0x80000000u) ? 0xFFFFFFFFu : 0x80000000u);
    atomicMax(dst, ((unsigned long long)kx << 32)
                   | (unsigned long long)(0xFFFFFFFFu - (unsigned int)rx));
    unsigned int uy = __float_as_uint(by);
    unsigned int ky = uy ^ ((uy & 0x80000000u) ? 0xFFFFFFFFu : 0x80000000u);
    atomicMax(dst + 1, ((unsigned long long)ky << 32)
                   | (unsigned long long)(0xFFFFFFFFu - (unsigned int)ry));
}

// Build pair table for forward: pairs[gate] = {i1*8, i2*8} (LDS byte offsets
// into float2 h). Layout: [0,1024) L1-AND, [1024,2048) L1-OR, [2048,3072)
// L2-AND, [3072,4096) L2-OR, [4096,4608) L3-AND, [4608,5120) L3-OR.
__global__ __launch_bounds__(256) void convert_kernel(const unsigned long long* __restrict__ packed,
                                                      uint2* __restrict__ pairs) {
    int i = blockIdx.x * 256 + threadIdx.x;
    if (i >= 5120) return;
    int l    = (i < 2048) ? 0 : ((i < 4096) ? 1 : 2);
    int half = (l == 2) ? 512 : 1024;
    int r    = i - l * 2048;
    int type = (r >= half) ? 1 : 0;            // 0=AND(c1,c2) 1=OR(d1,d2)
    int g    = r - type * half;
    int o1   = l * 4096 + 2 * type * half + g;
    int o2   = o1 + half;
    unsigned int i1 = 0xFFFFFFFFu - (unsigned int)(packed[o1] & 0xFFFFFFFFull);
    unsigned int i2 = 0xFFFFFFFFu - (unsigned int)(packed[o2] & 0xFFFFFFFFull);
    pairs[i] = make_uint2(i1 * 8u, i2 * 8u);
}

// One block = 2 batch rows, interleaved as float2 per feature slot.
// Slot numbering == original h indexing (x:0-511, 1-x:512-1023, const
// 1024/1025, L1 out 1026-3073, L2 out 3074-5121).
__global__ __launch_bounds__(512) void forward_kernel(const float* __restrict__ x,
                                                      const float* __restrict__ lin_w,
                                                      const uint2* __restrict__ pairs,
                                                      float* __restrict__ out) {
    __shared__ float2 hp[5122];
    __shared__ float2 red[8];
    const int t  = threadIdx.x;
    const int r0 = blockIdx.x * 2;
    const char* hb = (const char*)hp;

    // ---- stage h0: x, 1-x, constants (both rows packed) ----
    float xa = x[(size_t)r0 * 512 + t];
    float xb = x[(size_t)(r0 + 1) * 512 + t];
    // prefetch layer-1 pairs while staging
    uint2 pa0 = pairs[t], pa1 = pairs[512 + t];
    uint2 po0 = pairs[1024 + t], po1 = pairs[1536 + t];
    hp[t]       = make_float2(xa, xb);
    hp[512 + t] = make_float2(1.0f - xa, 1.0f - xb);
    if (t == 0) { hp[1024] = make_float2(1.0f, 1.0f); hp[1025] = make_float2(0.0f, 0.0f); }
    __syncthreads();

    // ---- layer 1: 1024 AND -> slots 1026.., 1024 OR -> slots 2050.. ----
    {
        float2 a0 = *(const float2*)(hb + pa0.x), b0 = *(const float2*)(hb + pa0.y);
        float2 a1 = *(const float2*)(hb + pa1.x), b1 = *(const float2*)(hb + pa1.y);
        float2 e0 = *(const float2*)(hb + po0.x), f0 = *(const float2*)(hb + po0.y);
        float2 e1 = *(const float2*)(hb + po1.x), f1 = *(const float2*)(hb + po1.y);
        hp[1026 + t]       = make_float2(a0.x * b0.x, a0.y * b0.y);
        hp[1538 + t]       = make_float2(a1.x * b1.x, a1.y * b1.y);
        hp[2050 + t]       = make_float2(1.0f - (1.0f - e0.x) * (1.0f - f0.x),
                                         1.0f - (1.0f - e0.y) * (1.0f - f0.y));
        hp[2562 + t]       = make_float2(1.0f - (1.0f - e1.x) * (1.0f - f1.x),
                                         1.0f - (1.0f - e1.y) * (1.0f - f1.y));
    }
    // prefetch layer-2 pairs (independent of the barrier)
    uint2 qa0 = pairs[2048 + t], qa1 = pairs[2560 + t];
    uint2 qo0 = pairs[3072 + t], qo1 = pairs[3584 + t];
    __syncthreads();

    // ---- layer 2: 1024 AND -> 3074.., 1024 OR -> 4098.. ----
    {
        float2 a0 = *(const float2*)(hb + qa0.x), b0 = *(const float2*)(hb + qa0.y);
        float2 a1 = *(const float2*)(hb + qa1.x), b1 = *(const float2*)(hb + qa1.y);
        float2 e0 = *(const float2*)(hb + qo0.x), f0 = *(const float2*)(hb + qo0.y);
        float2 e1 = *(const float2*)(hb + qo1.x), f1 = *(const float2*)(hb + qo1.y);
        hp[3074 + t]       = make_float2(a0.x * b0.x, a0.y * b0.y);
        hp[3586 + t]       = make_float2(a1.x * b1.x, a1.y * b1.y);
        hp[4098 + t]       = make_float2(1.0f - (1.0f - e0.x) * (1.0f - f0.x),
                                         1.0f - (1.0f - e0.y) * (1.0f - f0.y));
        hp[4610 + t]       = make_float2(1.0f - (1.0f - e1.x) * (1.0f - f1.x),
                                         1.0f - (1.0f - e1.y) * (1.0f - f1.y));
    }
    // prefetch layer-3 pairs + lin_w
    uint2 za = pairs[4096 + t], zo = pairs[4608 + t];
    float wA = lin_w[t], wO = lin_w[512 + t];
    __syncthreads();

    // ---- layer 3 (512 AND + 512 OR) fused with lin_w dot ----
    float2 s;
    {
        float2 a = *(const float2*)(hb + za.x), b = *(const float2*)(hb + za.y);
        float2 e = *(const float2*)(hb + zo.x), f = *(const float2*)(hb + zo.y);
        float cx = a.x * b.x, cy = a.y * b.y;
        float dx = 1.0f - (1.0f - e.x) * (1.0f - f.x);
        float dy = 1.0f - (1.0f - e.y) * (1.0f - f.y);
        s.x = wA * cx + wO * dx;
        s.y = wA * cy + wO * dy;
    }

    // ---- block reduction (8 waves) ----
    #pragma unroll
    for (int off = 32; off > 0; off >>= 1) {
        s.x += __shfl_down(s.x, off, 64);
        s.y += __shfl_down(s.y, off, 64);
    }
    if ((t & 63) == 0) red[t >> 6] = s;
    __syncthreads();
    if (t == 0) {
        float2 tot = red[0];
        #pragma unroll
        for (int i = 1; i < 8; ++i) { tot.x += red[i].x; tot.y += red[i].y; }
        *(float2*)(out + r0) = tot;
    }
}

extern "C" void kernel_launch(void* const* d_in, const int* in_sizes, int n_in,
                              void* d_out, int out_size, void* d_ws, size_t ws_size,
                              hipStream_t stream) {
    GatePtrs gp;
    for (int l = 0; l < 3; ++l) {
        for (int s = 0; s < 4; ++s) {
            gp.w[l * 4 + s] = (const float*)d_in[l * 8 + s];
            gp.g[l * 4 + s] = (const float*)d_in[l * 8 + 4 + s];
        }
    }
    const float* x     = (const float*)d_in[24];
    const float* lin_w = (const float*)d_in[25];
    float* out = (float*)d_out;

    unsigned long long* packed = (unsigned long long*)d_ws;
    uint2* pairs = (uint2*)((char*)d_ws + 10240 * sizeof(unsigned long long));

    hipMemsetAsync(d_ws, 0, 10240 * sizeof(unsigned long long), stream);

    dim3 gridA(2 /*col-pair blocks*/, 81 /*row chunks (max)*/, 12 /*gates*/);
    argmax_kernel<<<gridA, 256, 0, stream>>>(gp, packed);

    convert_kernel<<<20, 256, 0, stream>>>(packed, pairs);

    forward_kernel<<<16384, 512, 0, stream>>>(x, lin_w, pairs, out);
}

// Round 3
// 353.145 us; speedup vs baseline: 1.0826x; 1.0443x over previous
//
#include <hip/hip_runtime.h>
#include <hip/hip_fp16.h>
#include <stdint.h>

// ---------------------------------------------------------------------------
// RuleModel forward. ST-gumbel gate forward == exact one-hot column selector,
// so each h @ gate is a gather with index argmax_i(w[i,j]+g[i,j]).
// Fast path (ws >= 13.8MB): argmax_part (no atomics, per-chunk partials) ->
// reduce_pairs -> forward (4 rows/block, fp16-packed h, b64 LDS gathers).
// Fallback: memset -> atomic argmax -> convert -> forward.
// ---------------------------------------------------------------------------

struct GatePtrs {
    const float* w[12];
    const float* g[12];
};

__device__ __forceinline__ unsigned int sortkey(float f) {
    unsigned int u = __float_as_uint(f);
    return u ^ ((u & 0x80000000u) ? 0xFFFFFFFFu : 0x80000000u);
}

// ---------------- fast path: phase A (no atomics) ---------------------------
// partial layout (u64): per layer base pbs[l]; entry (slot, chunk, col) at
// pbs[l] + (slot*ch[l] + chunk)*dout[l] + col.  chunk = 16 rows.
__global__ __launch_bounds__(256) void argmax_part(GatePtrs gp,
                                                   unsigned long long* __restrict__ part) {
    const int dins[3]  = {1026, 3074, 5122};
    const int douts[3] = {1024, 1024, 512};
    const int chs[3]   = {65, 193, 321};
    const int pbs[3]   = {0, 266240, 1056768};
    int gate = blockIdx.z, layer = gate >> 2, slot = gate & 3;
    int din = dins[layer], dout = douts[layer], ch = chs[layer];
    int cols4 = dout >> 2;                   // 256 (L1/L2) or 128 (L3)
    int sub   = threadIdx.x / cols4;         // 0, or 0/1 for L3
    int c4    = threadIdx.x - sub * cols4;
    int chunk = blockIdx.y * (256 / cols4) + sub;
    if (chunk >= ch) return;
    int r0 = chunk * 16;
    int r1 = min(r0 + 16, din);
    const float* __restrict__ w = gp.w[gate] + (size_t)r0 * dout + 4 * c4;
    const float* __restrict__ g = gp.g[gate] + (size_t)r0 * dout + 4 * c4;
    float bx = -3.4e38f, by = bx, bz = bx, bw = bx;
    int ix = r0, iy = r0, iz = r0, iw = r0;
    #pragma unroll 8
    for (int i = r0; i < r1; ++i) {
        float4 wv = *(const float4*)w;
        float4 gv = *(const float4*)g;
        w += dout; g += dout;
        float vx = wv.x + gv.x, vy = wv.y + gv.y;
        float vz = wv.z + gv.z, vw = wv.w + gv.w;
        if (vx > bx) { bx = vx; ix = i; }    // strict > keeps first index
        if (vy > by) { by = vy; iy = i; }
        if (vz > bz) { bz = vz; iz = i; }
        if (vw > bw) { bw = vw; iw = i; }
    }
    unsigned long long* dst = part + pbs[layer]
                            + ((size_t)(slot * ch + chunk)) * dout + 4 * c4;
    dst[0] = ((unsigned long long)sortkey(bx) << 32) | (unsigned int)ix;
    dst[1] = ((unsigned long long)sortkey(by) << 32) | (unsigned int)iy;
    dst[2] = ((unsigned long long)sortkey(bz) << 32) | (unsigned int)iz;
    dst[3] = ((unsigned long long)sortkey(bw) << 32) | (unsigned int)iw;
}

// ---------------- fast path: phase B (reduce partials -> pair table) --------
// pf layout (ushort slot indices): entry 2i+e is input e of gate-pair i.
// i: [0,1024) L1-AND, [1024,2048) L1-OR, [2048,3072) L2-AND, [3072,4096)
// L2-OR, [4096,4608) L3-AND, [4608,5120) L3-OR.
__global__ __launch_bounds__(256) void reduce_pairs(const unsigned long long* __restrict__ part,
                                                    unsigned short* __restrict__ pf) {
    int j = blockIdx.x * 256 + threadIdx.x;
    if (j >= 10240) return;
    int i = j >> 1, e = j & 1;
    int l    = (i < 2048) ? 0 : ((i < 4096) ? 1 : 2);
    int half = (l == 2) ? 512 : 1024;
    int r    = i - l * 2048;
    int type = (r >= half) ? 1 : 0;
    int g    = r - type * half;
    int s    = 2 * type + e;                 // slot: c1,c2,d1,d2
    const int chs[3] = {65, 193, 321};
    const int pbs[3] = {0, 266240, 1056768};
    const int dts[3] = {1024, 1024, 512};
    int ch = chs[l], dout = dts[l];
    const unsigned long long* p = part + pbs[l] + (size_t)s * ch * dout + g;
    unsigned int bk = 0, brw = 0;
    #pragma unroll 8
    for (int c = 0; c < ch; ++c) {
        unsigned long long v = p[(size_t)c * dout];
        unsigned int k = (unsigned int)(v >> 32);
        if (k > bk) { bk = k; brw = (unsigned int)v; }  // ties -> earlier chunk
    }
    pf[j] = (unsigned short)brw;
}

// ---------------- fallback: atomic argmax + convert -------------------------
__global__ __launch_bounds__(256) void argmax_atomic(GatePtrs gp,
                                                     unsigned long long* __restrict__ packed) {
    const int dins[3]  = {1026, 3074, 5122};
    const int douts[3] = {1024, 1024, 512};
    const int offs[3]  = {0, 4096, 8192};
    int gate = blockIdx.z, layer = gate >> 2;
    int din = dins[layer], dout = douts[layer];
    int c2 = blockIdx.x * 256 + threadIdx.x;
    int r0 = blockIdx.y * 64;
    if (2 * c2 >= dout || r0 >= din) return;
    int r1 = min(r0 + 64, din);
    const float* __restrict__ w = gp.w[gate];
    const float* __restrict__ g = gp.g[gate];
    float bx = -3.4e38f, by = -3.4e38f;
    int rx = r0, ry = r0;
    #pragma unroll 8
    for (int i = r0; i < r1; ++i) {
        float2 wv = *(const float2*)(w + (size_t)i * dout + 2 * c2);
        float2 gv = *(const float2*)(g + (size_t)i * dout + 2 * c2);
        float vx = wv.x + gv.x, vy = wv.y + gv.y;
        if (vx > bx) { bx = vx; rx = i; }
        if (vy > by) { by = vy; ry = i; }
    }
    unsigned long long* dst = packed + offs[layer] + (gate & 3) * dout + 2 * c2;
    atomicMax(dst, ((unsigned long long)sortkey(bx) << 32)
                   | (unsigned long long)(0xFFFFFFFFu - (unsigned int)rx));
    atomicMax(dst + 1, ((unsigned long long)sortkey(by) << 32)
                   | (unsigned long long)(0xFFFFFFFFu - (unsigned int)ry));
}

__global__ __launch_bounds__(256) void convert_fb(const unsigned long long* __restrict__ packed,
                                                  ushort2* __restrict__ pf) {
    int i = blockIdx.x * 256 + threadIdx.x;
    if (i >= 5120) return;
    int l    = (i < 2048) ? 0 : ((i < 4096) ? 1 : 2);
    int half = (l == 2) ? 512 : 1024;
    int r    = i - l * 2048;
    int type = (r >= half) ? 1 : 0;
    int g    = r - type * half;
    int o1   = l * 4096 + 2 * type * half + g;
    int o2   = o1 + half;
    unsigned int i1 = 0xFFFFFFFFu - (unsigned int)(packed[o1] & 0xFFFFFFFFull);
    unsigned int i2 = 0xFFFFFFFFu - (unsigned int)(packed[o2] & 0xFFFFFFFFull);
    pf[i] = make_ushort2((unsigned short)i1, (unsigned short)i2);
}

// ---------------- forward: 4 rows/block, fp16 packed h ----------------------
__device__ __forceinline__ __half2 bc(unsigned int u) { return __builtin_bit_cast(__half2, u); }
__device__ __forceinline__ unsigned int cb(__half2 h) { return __builtin_bit_cast(unsigned int, h); }

__device__ __forceinline__ uint2 gat(const char* hb, unsigned int s) {
    return *(const uint2*)(hb + (s << 3));
}
__device__ __forceinline__ uint2 andg(uint2 a, uint2 b) {
    return make_uint2(cb(__hmul2(bc(a.x), bc(b.x))), cb(__hmul2(bc(a.y), bc(b.y))));
}
__device__ __forceinline__ uint2 org(uint2 a, uint2 b) {
    __half2 one = __float2half2_rn(1.0f);
    __half2 lo = __hsub2(one, __hmul2(__hsub2(one, bc(a.x)), __hsub2(one, bc(b.x))));
    __half2 hi = __hsub2(one, __hmul2(__hsub2(one, bc(a.y)), __hsub2(one, bc(b.y))));
    return make_uint2(cb(lo), cb(hi));
}

__global__ __launch_bounds__(512) void forward_kernel(const float* __restrict__ x,
                                                      const float* __restrict__ lin_w,
                                                      const ushort2* __restrict__ pairs,
                                                      float* __restrict__ out) {
    __shared__ uint2 h[5122];      // slot s = 4 rows of feature s, fp16 packed
    __shared__ float4 red[8];
    const int t  = threadIdx.x;
    const int r0 = blockIdx.x * 4;
    const char* hb = (const char*)h;

    // ---- stage h0: x, 1-x, constants (4 rows packed) ----
    float xa = x[(size_t)(r0 + 0) * 512 + t];
    float xb = x[(size_t)(r0 + 1) * 512 + t];
    float xc = x[(size_t)(r0 + 2) * 512 + t];
    float xd = x[(size_t)(r0 + 3) * 512 + t];
    ushort2 pa0 = pairs[t], pa1 = pairs[512 + t];
    ushort2 po0 = pairs[1024 + t], po1 = pairs[1536 + t];
    h[t]       = make_uint2(cb(__floats2half2_rn(xa, xb)), cb(__floats2half2_rn(xc, xd)));
    h[512 + t] = make_uint2(cb(__floats2half2_rn(1.f - xa, 1.f - xb)),
                            cb(__floats2half2_rn(1.f - xc, 1.f - xd)));
    if (t == 0) {
        unsigned int o = cb(__float2half2_rn(1.0f));
        h[1024] = make_uint2(o, o);
        h[1025] = make_uint2(0u, 0u);
    }
    __syncthreads();

    // ---- layer 1: AND -> 1026.., OR -> 2050.. ----
    {
        uint2 a0 = andg(gat(hb, pa0.x), gat(hb, pa0.y));
        uint2 a1 = andg(gat(hb, pa1.x), gat(hb, pa1.y));
        uint2 o0 = org(gat(hb, po0.x), gat(hb, po0.y));
        uint2 o1 = org(gat(hb, po1.x), gat(hb, po1.y));
        h[1026 + t] = a0; h[1538 + t] = a1;
        h[2050 + t] = o0; h[2562 + t] = o1;
    }
    ushort2 qa0 = pairs[2048 + t], qa1 = pairs[2560 + t];
    ushort2 qo0 = pairs[3072 + t], qo1 = pairs[3584 + t];
    __syncthreads();

    // ---- layer 2: AND -> 3074.., OR -> 4098.. ----
    {
        uint2 a0 = andg(gat(hb, qa0.x), gat(hb, qa0.y));
        uint2 a1 = andg(gat(hb, qa1.x), gat(hb, qa1.y));
        uint2 o0 = org(gat(hb, qo0.x), gat(hb, qo0.y));
        uint2 o1 = org(gat(hb, qo1.x), gat(hb, qo1.y));
        h[3074 + t] = a0; h[3586 + t] = a1;
        h[4098 + t] = o0; h[4610 + t] = o1;
    }
    ushort2 za = pairs[4096 + t], zo = pairs[4608 + t];
    float wA = lin_w[t], wO = lin_w[512 + t];
    __syncthreads();

    // ---- layer 3 fused with lin_w dot ----
    uint2 cg = andg(gat(hb, za.x), gat(hb, za.y));
    uint2 dg = org(gat(hb, zo.x), gat(hb, zo.y));
    float2 cl = __half22float2(bc(cg.x)), ch2 = __half22float2(bc(cg.y));
    float2 dl = __half22float2(bc(dg.x)), dh = __half22float2(bc(dg.y));
    float4 s;
    s.x = wA * cl.x  + wO * dl.x;
    s.y = wA * cl.y  + wO * dl.y;
    s.z = wA * ch2.x + wO * dh.x;
    s.w = wA * ch2.y + wO * dh.y;

    // ---- block reduction ----
    #pragma unroll
    for (int off = 32; off > 0; off >>= 1) {
        s.x += __shfl_down(s.x, off, 64);
        s.y += __shfl_down(s.y, off, 64);
        s.z += __shfl_down(s.z, off, 64);
        s.w += __shfl_down(s.w, off, 64);
    }
    if ((t & 63) == 0) red[t >> 6] = s;
    __syncthreads();
    if (t == 0) {
        float4 tot = red[0];
        #pragma unroll
        for (int i = 1; i < 8; ++i) {
            tot.x += red[i].x; tot.y += red[i].y;
            tot.z += red[i].z; tot.w += red[i].w;
        }
        *(float4*)(out + r0) = tot;
    }
}

extern "C" void kernel_launch(void* const* d_in, const int* in_sizes, int n_in,
                              void* d_out, int out_size, void* d_ws, size_t ws_size,
                              hipStream_t stream) {
    GatePtrs gp;
    for (int l = 0; l < 3; ++l)
        for (int s = 0; s < 4; ++s) {
            gp.w[l * 4 + s] = (const float*)d_in[l * 8 + s];
            gp.g[l * 4 + s] = (const float*)d_in[l * 8 + 4 + s];
        }
    const float* x     = (const float*)d_in[24];
    const float* lin_w = (const float*)d_in[25];
    float* out = (float*)d_out;

    const size_t partBytes = 1714176ull * 8ull;   // 13,713,408
    if (ws_size >= partBytes + 20480) {
        // fast path: no atomics, no memset
        unsigned long long* part = (unsigned long long*)d_ws;
        unsigned short* pf = (unsigned short*)((char*)d_ws + partBytes);
        dim3 ga(1, 193, 12);
        argmax_part<<<ga, 256, 0, stream>>>(gp, part);
        reduce_pairs<<<40, 256, 0, stream>>>(part, pf);
        forward_kernel<<<8192, 512, 0, stream>>>(x, lin_w, (const ushort2*)pf, out);
    } else {
        unsigned long long* packed = (unsigned long long*)d_ws;
        ushort2* pf = (ushort2*)((char*)d_ws + 10240 * 8);
        hipMemsetAsync(d_ws, 0, 10240 * 8, stream);
        dim3 ga(2, 81, 12);
        argmax_atomic<<<ga, 256, 0, stream>>>(gp, packed);
        convert_fb<<<20, 256, 0, stream>>>(packed, pf);
        forward_kernel<<<8192, 512, 0, stream>>>(x, lin_w, (const ushort2*)pf, out);
    }
}

// Round 4
// 343.238 us; speedup vs baseline: 1.1138x; 1.0289x over previous
//
#include <hip/hip_runtime.h>
#include <hip/hip_fp16.h>
#include <stdint.h>

// ---------------------------------------------------------------------------
// RuleModel forward. ST-gumbel gate forward == exact one-hot column selector,
// so each h @ gate is a gather with index argmax_i(w[i,j]+g[i,j]).
// Fast path: argmax_part (no atomics, explicit 8-load software pipeline) ->
// reduce_pairs2 (cooperative, coalesced) -> forward (4 rows/block, fp16 h).
// Fallback (small ws): memset -> atomic argmax -> convert -> forward.
// ---------------------------------------------------------------------------

struct GatePtrs {
    const float* w[12];
    const float* g[12];
};

__device__ __forceinline__ unsigned int sortkey(float f) {
    unsigned int u = __float_as_uint(f);
    return u ^ ((u & 0x80000000u) ? 0xFFFFFFFFu : 0x80000000u);
}

// ---------------- fast path: phase A ---------------------------------------
// partial layout (u64): per layer base pbs[l]; entry (slot, chunk, col) at
// pbs[l] + (slot*ch[l] + chunk)*dout[l] + col. chunk = 16 rows.
// value = (sortkey(best) << 32) | best_row.
__global__ __launch_bounds__(256) void argmax_part(GatePtrs gp,
                                                   unsigned long long* __restrict__ part) {
    const int dins[3]  = {1026, 3074, 5122};
    const int douts[3] = {1024, 1024, 512};
    const int chs[3]   = {65, 193, 321};
    const int pbs[3]   = {0, 266240, 1056768};
    int gate = blockIdx.z, layer = gate >> 2, slot = gate & 3;
    int din = dins[layer], dout = douts[layer], ch = chs[layer];
    int s4    = dout >> 2;                    // float4s per row
    int cols4 = s4;                           // 256 (L1/L2) or 128 (L3)
    int sub   = threadIdx.x / cols4;          // 0, or 0/1 for L3
    int c4    = threadIdx.x - sub * cols4;
    int chunk = blockIdx.y * (256 / cols4) + sub;
    if (chunk >= ch) return;
    int r0 = chunk * 16;
    int n  = min(16, din - r0);               // 16 or 2 (tail chunk)
    const float4* __restrict__ wp = (const float4*)gp.w[gate] + (size_t)r0 * s4 + c4;
    const float4* __restrict__ gq = (const float4*)gp.g[gate] + (size_t)r0 * s4 + c4;
    float bx = -3.4e38f, by = bx, bz = bx, bw = bx;
    int ix = r0, iy = r0, iz = r0, iw = r0;
    if (n == 16) {
        #pragma unroll
        for (int u = 0; u < 4; ++u) {
            float4 wv[4], gv[4];
            #pragma unroll
            for (int k = 0; k < 4; ++k) {     // 8 loads issued before any use
                wv[k] = wp[(size_t)(u * 4 + k) * s4];
                gv[k] = gq[(size_t)(u * 4 + k) * s4];
            }
            #pragma unroll
            for (int k = 0; k < 4; ++k) {
                int i = r0 + u * 4 + k;
                float vx = wv[k].x + gv[k].x, vy = wv[k].y + gv[k].y;
                float vz = wv[k].z + gv[k].z, vw = wv[k].w + gv[k].w;
                if (vx > bx) { bx = vx; ix = i; }   // strict > keeps first row
                if (vy > by) { by = vy; iy = i; }
                if (vz > bz) { bz = vz; iz = i; }
                if (vw > bw) { bw = vw; iw = i; }
            }
        }
    } else {
        for (int m = 0; m < n; ++m) {
            float4 wv = wp[(size_t)m * s4];
            float4 gv = gq[(size_t)m * s4];
            int i = r0 + m;
            float vx = wv.x + gv.x, vy = wv.y + gv.y;
            float vz = wv.z + gv.z, vw = wv.w + gv.w;
            if (vx > bx) { bx = vx; ix = i; }
            if (vy > by) { by = vy; iy = i; }
            if (vz > bz) { bz = vz; iz = i; }
            if (vw > bw) { bw = vw; iw = i; }
        }
    }
    unsigned long long* dst = part + pbs[layer]
                            + ((size_t)(slot * ch + chunk)) * dout + 4 * c4;
    dst[0] = ((unsigned long long)sortkey(bx) << 32) | (unsigned int)ix;
    dst[1] = ((unsigned long long)sortkey(by) << 32) | (unsigned int)iy;
    dst[2] = ((unsigned long long)sortkey(bz) << 32) | (unsigned int)iz;
    dst[3] = ((unsigned long long)sortkey(bw) << 32) | (unsigned int)iw;
}

// ---------------- fast path: phase B (cooperative reduce) -------------------
// 320 blocks x 256 threads: 32 columns x 8 chunk-lanes. Coalesced reads,
// LDS tree over chunk-lanes. pf[2i+e] = input-e slot index of gate-pair i.
__global__ __launch_bounds__(256) void reduce_pairs2(const unsigned long long* __restrict__ part,
                                                     unsigned short* __restrict__ pf) {
    __shared__ unsigned long long red[256];
    int t = threadIdx.x;
    int k = t >> 5, gi = t & 31;
    int C = blockIdx.x * 32;                  // global col-slot base
    int l, s, g0, half, dout, ch, pb;
    if (C < 4096)      { l = 0; s = C >> 10;          g0 = C & 1023;          half = 1024; dout = 1024; ch = 65;  pb = 0; }
    else if (C < 8192) { l = 1; s = (C - 4096) >> 10; g0 = (C - 4096) & 1023; half = 1024; dout = 1024; ch = 193; pb = 266240; }
    else               { l = 2; s = (C - 8192) >> 9;  g0 = (C - 8192) & 511;  half = 512;  dout = 512;  ch = 321; pb = 1056768; }
    int g = g0 + gi;
    const unsigned long long* __restrict__ p = part + pb + (size_t)(s * ch) * dout + g;
    unsigned long long best = 0;
    for (int c = k; c < ch; c += 8) {
        unsigned long long v = p[(size_t)c * dout];
        if ((unsigned int)(v >> 32) > (unsigned int)(best >> 32)) best = v;
    }
    red[t] = best;
    __syncthreads();
    #pragma unroll
    for (int st = 4; st >= 1; st >>= 1) {
        if (k < st) {
            unsigned long long o = red[t + st * 32];
            if ((unsigned int)(o >> 32) > (unsigned int)(best >> 32)) best = o;
            red[t] = best;
        }
        __syncthreads();
    }
    if (k == 0) {
        int type = s >> 1, e = s & 1;
        int j = 2 * (l * 2048 + type * half + g) + e;
        pf[j] = (unsigned short)best;         // low 16 bits = row index (<5122)
    }
}

// ---------------- fallback: atomic argmax + convert -------------------------
__global__ __launch_bounds__(256) void argmax_atomic(GatePtrs gp,
                                                     unsigned long long* __restrict__ packed) {
    const int dins[3]  = {1026, 3074, 5122};
    const int douts[3] = {1024, 1024, 512};
    const int offs[3]  = {0, 4096, 8192};
    int gate = blockIdx.z, layer = gate >> 2;
    int din = dins[layer], dout = douts[layer];
    int c2 = blockIdx.x * 256 + threadIdx.x;
    int r0 = blockIdx.y * 64;
    if (2 * c2 >= dout || r0 >= din) return;
    int r1 = min(r0 + 64, din);
    const float* __restrict__ w = gp.w[gate];
    const float* __restrict__ g = gp.g[gate];
    float bx = -3.4e38f, by = -3.4e38f;
    int rx = r0, ry = r0;
    #pragma unroll 8
    for (int i = r0; i < r1; ++i) {
        float2 wv = *(const float2*)(w + (size_t)i * dout + 2 * c2);
        float2 gv = *(const float2*)(g + (size_t)i * dout + 2 * c2);
        float vx = wv.x + gv.x, vy = wv.y + gv.y;
        if (vx > bx) { bx = vx; rx = i; }
        if (vy > by) { by = vy; ry = i; }
    }
    unsigned long long* dst = packed + offs[layer] + (gate & 3) * dout + 2 * c2;
    atomicMax(dst, ((unsigned long long)sortkey(bx) << 32)
                   | (unsigned long long)(0xFFFFFFFFu - (unsigned int)rx));
    atomicMax(dst + 1, ((unsigned long long)sortkey(by) << 32)
                   | (unsigned long long)(0xFFFFFFFFu - (unsigned int)ry));
}

__global__ __launch_bounds__(256) void convert_fb(const unsigned long long* __restrict__ packed,
                                                  ushort2* __restrict__ pf) {
    int i = blockIdx.x * 256 + threadIdx.x;
    if (i >= 5120) return;
    int l    = (i < 2048) ? 0 : ((i < 4096) ? 1 : 2);
    int half = (l == 2) ? 512 : 1024;
    int r    = i - l * 2048;
    int type = (r >= half) ? 1 : 0;
    int g    = r - type * half;
    int o1   = l * 4096 + 2 * type * half + g;
    int o2   = o1 + half;
    unsigned int i1 = 0xFFFFFFFFu - (unsigned int)(packed[o1] & 0xFFFFFFFFull);
    unsigned int i2 = 0xFFFFFFFFu - (unsigned int)(packed[o2] & 0xFFFFFFFFull);
    pf[i] = make_ushort2((unsigned short)i1, (unsigned short)i2);
}

// ---------------- forward: 4 rows/block, fp16 packed h ----------------------
__device__ __forceinline__ __half2 bc(unsigned int u) { return __builtin_bit_cast(__half2, u); }
__device__ __forceinline__ unsigned int cb(__half2 h) { return __builtin_bit_cast(unsigned int, h); }

__device__ __forceinline__ uint2 gat(const char* hb, unsigned int s) {
    return *(const uint2*)(hb + (s << 3));
}
__device__ __forceinline__ uint2 andg(uint2 a, uint2 b) {
    return make_uint2(cb(__hmul2(bc(a.x), bc(b.x))), cb(__hmul2(bc(a.y), bc(b.y))));
}
__device__ __forceinline__ uint2 org(uint2 a, uint2 b) {
    __half2 one = __float2half2_rn(1.0f);
    __half2 lo = __hsub2(one, __hmul2(__hsub2(one, bc(a.x)), __hsub2(one, bc(b.x))));
    __half2 hi = __hsub2(one, __hmul2(__hsub2(one, bc(a.y)), __hsub2(one, bc(b.y))));
    return make_uint2(cb(lo), cb(hi));
}

__global__ __launch_bounds__(512) void forward_kernel(const float* __restrict__ x,
                                                      const float* __restrict__ lin_w,
                                                      const ushort2* __restrict__ pairs,
                                                      float* __restrict__ out) {
    __shared__ uint2 h[5122];      // slot s = 4 rows of feature s, fp16 packed
    __shared__ float4 red[8];
    const int t  = threadIdx.x;
    const int r0 = blockIdx.x * 4;
    const char* hb = (const char*)h;

    float xa = x[(size_t)(r0 + 0) * 512 + t];
    float xb = x[(size_t)(r0 + 1) * 512 + t];
    float xc = x[(size_t)(r0 + 2) * 512 + t];
    float xd = x[(size_t)(r0 + 3) * 512 + t];
    ushort2 pa0 = pairs[t], pa1 = pairs[512 + t];
    ushort2 po0 = pairs[1024 + t], po1 = pairs[1536 + t];
    h[t]       = make_uint2(cb(__floats2half2_rn(xa, xb)), cb(__floats2half2_rn(xc, xd)));
    h[512 + t] = make_uint2(cb(__floats2half2_rn(1.f - xa, 1.f - xb)),
                            cb(__floats2half2_rn(1.f - xc, 1.f - xd)));
    if (t == 0) {
        unsigned int o = cb(__float2half2_rn(1.0f));
        h[1024] = make_uint2(o, o);
        h[1025] = make_uint2(0u, 0u);
    }
    __syncthreads();

    {
        uint2 a0 = andg(gat(hb, pa0.x), gat(hb, pa0.y));
        uint2 a1 = andg(gat(hb, pa1.x), gat(hb, pa1.y));
        uint2 o0 = org(gat(hb, po0.x), gat(hb, po0.y));
        uint2 o1 = org(gat(hb, po1.x), gat(hb, po1.y));
        h[1026 + t] = a0; h[1538 + t] = a1;
        h[2050 + t] = o0; h[2562 + t] = o1;
    }
    ushort2 qa0 = pairs[2048 + t], qa1 = pairs[2560 + t];
    ushort2 qo0 = pairs[3072 + t], qo1 = pairs[3584 + t];
    __syncthreads();

    {
        uint2 a0 = andg(gat(hb, qa0.x), gat(hb, qa0.y));
        uint2 a1 = andg(gat(hb, qa1.x), gat(hb, qa1.y));
        uint2 o0 = org(gat(hb, qo0.x), gat(hb, qo0.y));
        uint2 o1 = org(gat(hb, qo1.x), gat(hb, qo1.y));
        h[3074 + t] = a0; h[3586 + t] = a1;
        h[4098 + t] = o0; h[4610 + t] = o1;
    }
    ushort2 za = pairs[4096 + t], zo = pairs[4608 + t];
    float wA = lin_w[t], wO = lin_w[512 + t];
    __syncthreads();

    uint2 cg = andg(gat(hb, za.x), gat(hb, za.y));
    uint2 dg = org(gat(hb, zo.x), gat(hb, zo.y));
    float2 cl = __half22float2(bc(cg.x)), ch2 = __half22float2(bc(cg.y));
    float2 dl = __half22float2(bc(dg.x)), dh = __half22float2(bc(dg.y));
    float4 s;
    s.x = wA * cl.x  + wO * dl.x;
    s.y = wA * cl.y  + wO * dl.y;
    s.z = wA * ch2.x + wO * dh.x;
    s.w = wA * ch2.y + wO * dh.y;

    #pragma unroll
    for (int off = 32; off > 0; off >>= 1) {
        s.x += __shfl_down(s.x, off, 64);
        s.y += __shfl_down(s.y, off, 64);
        s.z += __shfl_down(s.z, off, 64);
        s.w += __shfl_down(s.w, off, 64);
    }
    if ((t & 63) == 0) red[t >> 6] = s;
    __syncthreads();
    if (t == 0) {
        float4 tot = red[0];
        #pragma unroll
        for (int i = 1; i < 8; ++i) {
            tot.x += red[i].x; tot.y += red[i].y;
            tot.z += red[i].z; tot.w += red[i].w;
        }
        *(float4*)(out + r0) = tot;
    }
}

extern "C" void kernel_launch(void* const* d_in, const int* in_sizes, int n_in,
                              void* d_out, int out_size, void* d_ws, size_t ws_size,
                              hipStream_t stream) {
    GatePtrs gp;
    for (int l = 0; l < 3; ++l)
        for (int s = 0; s < 4; ++s) {
            gp.w[l * 4 + s] = (const float*)d_in[l * 8 + s];
            gp.g[l * 4 + s] = (const float*)d_in[l * 8 + 4 + s];
        }
    const float* x     = (const float*)d_in[24];
    const float* lin_w = (const float*)d_in[25];
    float* out = (float*)d_out;

    const size_t partBytes = 1714176ull * 8ull;   // 13,713,408
    if (ws_size >= partBytes + 20480) {
        unsigned long long* part = (unsigned long long*)d_ws;
        unsigned short* pf = (unsigned short*)((char*)d_ws + partBytes);
        dim3 ga(1, 193, 12);
        argmax_part<<<ga, 256, 0, stream>>>(gp, part);
        reduce_pairs2<<<320, 256, 0, stream>>>(part, pf);
        forward_kernel<<<8192, 512, 0, stream>>>(x, lin_w, (const ushort2*)pf, out);
    } else {
        unsigned long long* packed = (unsigned long long*)d_ws;
        ushort2* pf = (ushort2*)((char*)d_ws + 10240 * 8);
        hipMemsetAsync(d_ws, 0, 10240 * 8, stream);
        dim3 ga(2, 81, 12);
        argmax_atomic<<<ga, 256, 0, stream>>>(gp, packed);
        convert_fb<<<20, 256, 0, stream>>>(packed, pf);
        forward_kernel<<<8192, 512, 0, stream>>>(x, lin_w, (const ushort2*)pf, out);
    }
}